// Round 3
// baseline (1414.206 us; speedup 1.0000x reference)
//
#include <hip/hip_runtime.h>

typedef _Float16 f16;
typedef _Float16 half8 __attribute__((ext_vector_type(8)));
typedef _Float16 half4v __attribute__((ext_vector_type(4)));
typedef float f32x4 __attribute__((ext_vector_type(4)));

// x: [128][512][128] f32, alpha: [128] f32, A: [128][128][128] f32 (i,j,k), Omega: [128][32] f32
// out: [128][32] f32
// Phase 1: B[q][i][k] = sum_j A[i][j][k] * x[n(q), t(q), j]  (fp16 store, fp32 acc)
// Phase 2: h <- B_t^T h sequentially, fp32.

// ---------- convert x -> fp16 ----------
__global__ void k_cvt_x(const float* __restrict__ in, f16* __restrict__ out) {
    int idx = blockIdx.x * blockDim.x + threadIdx.x;
    float4 v = ((const float4*)in)[idx];
    half4v o;
    o[0] = (f16)v.x; o[1] = (f16)v.y; o[2] = (f16)v.z; o[3] = (f16)v.w;
    ((half4v*)out)[idx] = o;
}

// ---------- transpose-convert A: Af2[i][k][j] = A[i][j][k] ----------
__global__ void k_cvt_A(const float* __restrict__ A, f16* __restrict__ Af2) {
    int o = blockIdx.x * blockDim.x + threadIdx.x;
    int i = o >> 14;
    int k = (o >> 7) & 127;
    int j = o & 127;
    Af2[o] = (f16)A[(i << 14) + (j << 7) + k];
}

// ---------- phase 1 GEMM: persistent pipelined ----------
// grid = 512 blocks = 128 i * 4; block handles qtPerBlock qtiles (qtile = (bx&3) + 4*s)
// LDS: lA (A row-tile, resident) + lX (X tile / C stage), 64 KB total -> 2 blocks/CU.
__global__ __launch_bounds__(256, 2)
void k_gemm(const f16* __restrict__ Af2, const f16* __restrict__ Xh,
            f16* __restrict__ B, int t0, int logTc, int qtPerBlock) {
    __shared__ f16 lA[128 * 128];   // [k][j] swizzled, resident
    __shared__ f16 lX[128 * 128];   // [q][j] swizzled; reused as C-stage
    const int bx = blockIdx.x;
    const int i = bx >> 2;
    const int qt0 = bx & 3;
    const int tid = threadIdx.x;
    const int row = tid >> 4;       // 0..15
    const int ch = tid & 15;        // 16B chunk
    const int Tcm1 = (1 << logTc) - 1;

    // load A row-tile once
    {
        const f16* srcA = Af2 + ((size_t)i << 14);
#pragma unroll
        for (int r = 0; r < 128; r += 16) {
            int rr = row + r;
            uint4 v = *(const uint4*)(srcA + (rr << 7) + (ch << 3));
            *(uint4*)(&lA[(rr << 7) + ((ch ^ (rr & 15)) << 3)]) = v;
        }
    }

    uint4 xr[8];
    auto loadX = [&](int qtile) {
#pragma unroll
        for (int r = 0; r < 8; ++r) {
            int rr = (r << 4) + row;
            int qr = (qtile << 7) + rr;
            int n = qr >> logTc;
            int trel = qr & Tcm1;
            xr[r] = *(const uint4*)(Xh + (((size_t)(n << 9) + t0 + trel) << 7) + (ch << 3));
        }
    };
    auto xToLds = [&]() {
#pragma unroll
        for (int r = 0; r < 8; ++r) {
            int rr = (r << 4) + row;
            *(uint4*)(&lX[(rr << 7) + ((ch ^ (rr & 15)) << 3)]) = xr[r];
        }
    };

    loadX(qt0);
    xToLds();
    __syncthreads();

    const int wave = tid >> 6;
    const int lane = tid & 63;
    const int l15 = lane & 15;
    const int l4 = lane >> 4;

    for (int s = 0; s < qtPerBlock; ++s) {
        const int qtile = qt0 + (s << 2);
        const int qtileN = (s + 1 < qtPerBlock) ? qt0 + ((s + 1) << 2) : qt0;
        // prefetch next X tile into registers (covered by compute+epilogue)
        loadX(qtileN);

        f32x4 acc[8][2] = {};
#pragma unroll
        for (int ks = 0; ks < 4; ++ks) {
            const int c = (ks << 2) + l4;
            half8 afr[8], bfr[2];
#pragma unroll
            for (int mt = 0; mt < 8; ++mt) {
                int rowA = (mt << 4) + l15;
                afr[mt] = *(const half8*)(&lA[(rowA << 7) + ((c ^ l15) << 3)]);
            }
#pragma unroll
            for (int qt = 0; qt < 2; ++qt) {
                int rowX = (wave << 5) + (qt << 4) + l15;
                bfr[qt] = *(const half8*)(&lX[(rowX << 7) + ((c ^ l15) << 3)]);
            }
#pragma unroll
            for (int mt = 0; mt < 8; ++mt)
#pragma unroll
                for (int qt = 0; qt < 2; ++qt)
                    acc[mt][qt] = __builtin_amdgcn_mfma_f32_16x16x32_f16(
                        afr[mt], bfr[qt], acc[mt][qt], 0, 0, 0);
        }

        __syncthreads();            // all waves done reading lX
        // stage C tile into lX (XOR-swizzled)
#pragma unroll
        for (int mt = 0; mt < 8; ++mt)
#pragma unroll
            for (int qt = 0; qt < 2; ++qt) {
                int q = (wave << 5) + (qt << 4) + l15;       // q & 15 == l15
                int chunk = (mt << 1) + (l4 >> 1);
                int hf = l4 & 1;
                half4v o;
                o[0] = (f16)acc[mt][qt][0];
                o[1] = (f16)acc[mt][qt][1];
                o[2] = (f16)acc[mt][qt][2];
                o[3] = (f16)acc[mt][qt][3];
                *(half4v*)(&lX[(q << 7) + (((chunk ^ l15) << 3) + (hf << 2))]) = o;
            }
        __syncthreads();
        // coalesced store: 4 q-rows x 256 B per instruction
        {
            const int lr = lane >> 4;
            const int lc = lane & 15;
#pragma unroll
            for (int it = 0; it < 8; ++it) {
                int q = (wave << 5) + (it << 2) + lr;
                uint4 v = *(const uint4*)(&lX[(q << 7) + ((lc ^ (q & 15)) << 3)]);
                size_t qg = (size_t)((qtile << 7) + q);
                *(uint4*)(B + (qg << 14) + (i << 7) + (lc << 3)) = v;
            }
        }
        __syncthreads();            // C ds_reads done before overwriting lX
        xToLds();
        __syncthreads();
    }
}

// ---------- phase 2: sequential chain, depth-4 register prefetch ----------
__global__ __launch_bounds__(256, 1)
void k_chain(const f16* __restrict__ B, float* __restrict__ hstate,
             const float* __restrict__ alpha, const float* __restrict__ Om,
             float* __restrict__ out, int Tc, int first, int last) {
    __shared__ float hl[128];
    __shared__ float part[16][132];
    const int n = blockIdx.x;
    const int tid = threadIdx.x;
    const int kg = tid & 15;
    const int iq = tid >> 4;

    if (tid < 128) hl[tid] = first ? alpha[tid] : hstate[(n << 7) + tid];
    __syncthreads();

    const f16* bbase = B + (((size_t)n * Tc) << 14) + (iq << 10) + (kg << 3);
    half8 buf[4][8];
#pragma unroll
    for (int s = 0; s < 4; ++s)
#pragma unroll
        for (int ii = 0; ii < 8; ++ii)
            buf[s][ii] = *(const half8*)(bbase + ((size_t)s << 14) + (ii << 7));

    for (int t = 0; t < Tc; t += 4) {
#pragma unroll
        for (int s = 0; s < 4; ++s) {
            float4 h0 = *(const float4*)&hl[iq << 3];
            float4 h1 = *(const float4*)&hl[(iq << 3) + 4];
            float acc[8] = {0, 0, 0, 0, 0, 0, 0, 0};
#pragma unroll
            for (int ii = 0; ii < 4; ++ii) {
                float hv = (&h0.x)[ii];
#pragma unroll
                for (int j = 0; j < 8; ++j)
                    acc[j] += hv * (float)buf[s][ii][j];
            }
#pragma unroll
            for (int ii = 0; ii < 4; ++ii) {
                float hv = (&h1.x)[ii];
#pragma unroll
                for (int j = 0; j < 8; ++j)
                    acc[j] += hv * (float)buf[s][ii + 4][j];
            }
            int tn = t + s + 4;
            if (tn < Tc) {
#pragma unroll
                for (int ii = 0; ii < 8; ++ii)
                    buf[s][ii] = *(const half8*)(bbase + ((size_t)tn << 14) + (ii << 7));
            }
            *(float4*)(&part[iq][kg << 3])       = make_float4(acc[0], acc[1], acc[2], acc[3]);
            *(float4*)(&part[iq][(kg << 3) + 4]) = make_float4(acc[4], acc[5], acc[6], acc[7]);
            __syncthreads();
            if (tid < 128) {
                float s0 = part[0][tid] + part[1][tid];
                float s1 = part[2][tid] + part[3][tid];
                float s2 = part[4][tid] + part[5][tid];
                float s3 = part[6][tid] + part[7][tid];
                s0 += part[8][tid] + part[9][tid];
                s1 += part[10][tid] + part[11][tid];
                s2 += part[12][tid] + part[13][tid];
                s3 += part[14][tid] + part[15][tid];
                hl[tid] = (s0 + s1) + (s2 + s3);
            }
            __syncthreads();
        }
    }

    if (!last) {
        if (tid < 128) hstate[(n << 7) + tid] = hl[tid];
    } else if (tid < 32) {
        float s = 0.f;
        for (int i2 = 0; i2 < 128; ++i2) s += hl[i2] * Om[(i2 << 5) + tid];
        out[(n << 5) + tid] = s;
    }
}

extern "C" void kernel_launch(void* const* d_in, const int* in_sizes, int n_in,
                              void* d_out, int out_size, void* d_ws, size_t ws_size,
                              hipStream_t stream) {
    const float* x     = (const float*)d_in[0];
    const float* alpha = (const float*)d_in[1];
    const float* A     = (const float*)d_in[2];
    const float* Om    = (const float*)d_in[3];
    float* out = (float*)d_out;

    char* ws = (char*)d_ws;
    f16*   Af2    = (f16*)ws;                          // 4 MB  [i][k][j]
    f16*   Xh     = (f16*)(ws + ((size_t)4 << 20));    // 16 MB [n*512+t][j]
    float* hstate = (float*)(ws + ((size_t)20 << 20)); // 64 KB
    f16*   Bc     = (f16*)(ws + ((size_t)21 << 20));   // Tc*4 MB chunk

    int Tc = 32;  // 128 MB chunk -> LLC resident
    while (Tc > 4 && ((size_t)21 << 20) + ((size_t)Tc << 22) > ws_size) Tc >>= 1;
    int logTc = 31 - __builtin_clz(Tc);
    int nch = 512 / Tc;
    int qtPerBlock = Tc / 4;   // 4 blocks per i-row

    k_cvt_x<<<8192, 256, 0, stream>>>(x, Xh);
    k_cvt_A<<<8192, 256, 0, stream>>>(A, Af2);

    for (int c = 0; c < nch; ++c) {
        k_gemm<<<512, 256, 0, stream>>>(Af2, Xh, Bc, c * Tc, logTc, qtPerBlock);
        k_chain<<<128, 256, 0, stream>>>(Bc, hstate, alpha, Om, out,
                                         Tc, c == 0, c == nch - 1);
    }
    (void)in_sizes; (void)n_in; (void)out_size;
}

// Round 4
// 966.422 us; speedup vs baseline: 1.4633x; 1.4633x over previous
//
#include <hip/hip_runtime.h>

typedef _Float16 f16;
typedef _Float16 half8 __attribute__((ext_vector_type(8)));
typedef _Float16 half4v __attribute__((ext_vector_type(4)));
typedef float f32x4 __attribute__((ext_vector_type(4)));

// x: [128][512][128] f32, alpha: [128] f32, A: [128][128][128] f32 (i,j,k), Omega: [128][32] f32
// out: [128][32] f32
// Phase 1: B[q][i][k] = sum_j A[i][j][k] * x[n(q), t(q), j]  (fp16 store, fp32 acc)
// Phase 2: h <- B_t^T h sequentially, fp32.
// Overlap: dispatch D_c = chain(c) [blocks 0..127] + gemm(c+1) [blocks 128..]; stream
// order between dispatches is the only synchronization (no barriers/events).

// ---------- convert x -> fp16 ----------
__global__ void k_cvt_x(const float* __restrict__ in, f16* __restrict__ out) {
    int idx = blockIdx.x * blockDim.x + threadIdx.x;
    float4 v = ((const float4*)in)[idx];
    half4v o;
    o[0] = (f16)v.x; o[1] = (f16)v.y; o[2] = (f16)v.z; o[3] = (f16)v.w;
    ((half4v*)out)[idx] = o;
}

// ---------- transpose-convert A: Af2[i][k][j] = A[i][j][k] ----------
__global__ void k_cvt_A(const float* __restrict__ A, f16* __restrict__ Af2) {
    int o = blockIdx.x * blockDim.x + threadIdx.x;
    int i = o >> 14;
    int k = (o >> 7) & 127;
    int j = o & 127;
    Af2[o] = (f16)A[(i << 14) + (j << 7) + k];
}

// ================= gemm body (R2 structure, VGPR-lean: no reg prefetch) ============
// block: fixed i, 128-q tile. M=k=128, N=q=128, K=j=128. lA/lX are 32 KB each.
__device__ __forceinline__
void gemm_body(f16* lA, f16* lX, const f16* __restrict__ Af2, const f16* __restrict__ Xh,
               f16* __restrict__ B, int t0, int logTc, int qtile, int i, int tid) {
    const int row = tid >> 4;
    const int ch = tid & 15;
    const int Tcm1 = (1 << logTc) - 1;

    {
        const f16* srcA = Af2 + ((size_t)i << 14);
#pragma unroll
        for (int r = 0; r < 128; r += 16) {
            int rr = row + r;
            uint4 v = *(const uint4*)(srcA + (rr << 7) + (ch << 3));
            *(uint4*)(&lA[(rr << 7) + ((ch ^ (rr & 15)) << 3)]) = v;
        }
#pragma unroll
        for (int r = 0; r < 128; r += 16) {
            int rr = row + r;
            int qr = (qtile << 7) + rr;
            int n = qr >> logTc;
            int trel = qr & Tcm1;
            const f16* srcX = Xh + (((size_t)(n << 9) + t0 + trel) << 7);
            uint4 v = *(const uint4*)(srcX + (ch << 3));
            *(uint4*)(&lX[(rr << 7) + ((ch ^ (rr & 15)) << 3)]) = v;
        }
    }
    __syncthreads();

    const int wave = tid >> 6;
    const int lane = tid & 63;
    const int l15 = lane & 15;
    const int l4 = lane >> 4;
    f32x4 acc[8][2] = {};

#pragma unroll
    for (int ks = 0; ks < 4; ++ks) {
        const int c = (ks << 2) + l4;
        half8 afr[8], bfr[2];
#pragma unroll
        for (int mt = 0; mt < 8; ++mt) {
            int rowA = (mt << 4) + l15;
            afr[mt] = *(const half8*)(&lA[(rowA << 7) + ((c ^ l15) << 3)]);
        }
#pragma unroll
        for (int qt = 0; qt < 2; ++qt) {
            int rowX = (wave << 5) + (qt << 4) + l15;
            bfr[qt] = *(const half8*)(&lX[(rowX << 7) + ((c ^ l15) << 3)]);
        }
#pragma unroll
        for (int mt = 0; mt < 8; ++mt)
#pragma unroll
            for (int qt = 0; qt < 2; ++qt)
                acc[mt][qt] = __builtin_amdgcn_mfma_f32_16x16x32_f16(
                    afr[mt], bfr[qt], acc[mt][qt], 0, 0, 0);
    }

    // epilogue: stage C tile in lA (XOR-swizzled), then coalesced dwordx4 stores
    __syncthreads();
    f16* stage = lA;
#pragma unroll
    for (int mt = 0; mt < 8; ++mt)
#pragma unroll
        for (int qt = 0; qt < 2; ++qt) {
            int q = (wave << 5) + (qt << 4) + l15;          // q & 15 == l15
            int chunk = (mt << 1) + (l4 >> 1);
            int hf = l4 & 1;
            half4v o;
            o[0] = (f16)acc[mt][qt][0];
            o[1] = (f16)acc[mt][qt][1];
            o[2] = (f16)acc[mt][qt][2];
            o[3] = (f16)acc[mt][qt][3];
            *(half4v*)(&stage[(q << 7) + (((chunk ^ l15) << 3) + (hf << 2))]) = o;
        }
    __syncthreads();
    {
        const int lr = lane >> 4;
        const int lc = lane & 15;
#pragma unroll
        for (int it = 0; it < 8; ++it) {
            int q = (wave << 5) + (it << 2) + lr;
            uint4 v = *(const uint4*)(&stage[(q << 7) + ((lc ^ (q & 15)) << 3)]);
            size_t qg = (size_t)((qtile << 7) + q);
            *(uint4*)(B + (qg << 14) + (i << 7) + (lc << 3)) = v;
        }
    }
}

// ================= chain body (R2 structure, depth-4 reg prefetch) =================
__device__ __forceinline__
void chain_body(float* hl, float (*part)[132], const f16* __restrict__ B,
                float* __restrict__ hstate, const float* __restrict__ alpha,
                const float* __restrict__ Om, float* __restrict__ out,
                int Tc, int first, int last, int n, int tid) {
    const int kg = tid & 15;
    const int iq = tid >> 4;

    if (tid < 128) hl[tid] = first ? alpha[tid] : hstate[(n << 7) + tid];
    __syncthreads();

    const f16* bbase = B + (((size_t)n * Tc) << 14) + (iq << 10) + (kg << 3);
    half8 buf[4][8];
#pragma unroll
    for (int s = 0; s < 4; ++s)
#pragma unroll
        for (int ii = 0; ii < 8; ++ii)
            buf[s][ii] = *(const half8*)(bbase + ((size_t)s << 14) + (ii << 7));

    for (int t = 0; t < Tc; t += 4) {
#pragma unroll
        for (int s = 0; s < 4; ++s) {
            float4 h0 = *(const float4*)&hl[iq << 3];
            float4 h1 = *(const float4*)&hl[(iq << 3) + 4];
            float acc[8] = {0, 0, 0, 0, 0, 0, 0, 0};
#pragma unroll
            for (int ii = 0; ii < 4; ++ii) {
                float hv = (&h0.x)[ii];
#pragma unroll
                for (int j = 0; j < 8; ++j)
                    acc[j] += hv * (float)buf[s][ii][j];
            }
#pragma unroll
            for (int ii = 0; ii < 4; ++ii) {
                float hv = (&h1.x)[ii];
#pragma unroll
                for (int j = 0; j < 8; ++j)
                    acc[j] += hv * (float)buf[s][ii + 4][j];
            }
            int tn = t + s + 4;
            if (tn < Tc) {
#pragma unroll
                for (int ii = 0; ii < 8; ++ii)
                    buf[s][ii] = *(const half8*)(bbase + ((size_t)tn << 14) + (ii << 7));
            }
            *(float4*)(&part[iq][kg << 3])       = make_float4(acc[0], acc[1], acc[2], acc[3]);
            *(float4*)(&part[iq][(kg << 3) + 4]) = make_float4(acc[4], acc[5], acc[6], acc[7]);
            __syncthreads();
            if (tid < 128) {
                float s0 = part[0][tid] + part[1][tid];
                float s1 = part[2][tid] + part[3][tid];
                float s2 = part[4][tid] + part[5][tid];
                float s3 = part[6][tid] + part[7][tid];
                s0 += part[8][tid] + part[9][tid];
                s1 += part[10][tid] + part[11][tid];
                s2 += part[12][tid] + part[13][tid];
                s3 += part[14][tid] + part[15][tid];
                hl[tid] = (s0 + s1) + (s2 + s3);
            }
            __syncthreads();
        }
    }

    if (!last) {
        if (tid < 128) hstate[(n << 7) + tid] = hl[tid];
    } else if (tid < 32) {
        float s = 0.f;
        for (int i2 = 0; i2 < 128; ++i2) s += hl[i2] * Om[(i2 << 5) + tid];
        out[(n << 5) + tid] = s;
    }
}

// ================= kernels =================
__global__ __launch_bounds__(256, 2)
void k_gemm(const f16* __restrict__ Af2, const f16* __restrict__ Xh,
            f16* __restrict__ B, int t0, int logTc) {
    __shared__ __align__(16) char smem[65536];
    gemm_body((f16*)smem, (f16*)(smem + 32768), Af2, Xh, B, t0, logTc,
              blockIdx.x, blockIdx.y, threadIdx.x);
}

__global__ __launch_bounds__(256, 2)
void k_chain(const f16* __restrict__ B, float* __restrict__ hstate,
             const float* __restrict__ alpha, const float* __restrict__ Om,
             float* __restrict__ out, int Tc, int first, int last) {
    __shared__ __align__(16) char smem[16384];
    chain_body((float*)smem, (float(*)[132])(smem + 512), B, hstate, alpha, Om, out,
               Tc, first, last, blockIdx.x, threadIdx.x);
}

// fused: blocks 0..127 run chain(c) on Br; blocks 128.. run gemm(c+1) into Bw.
__global__ __launch_bounds__(256, 2)
void k_fused(const f16* __restrict__ Af2, const f16* __restrict__ Xh,
             f16* __restrict__ Bw, const f16* __restrict__ Br,
             float* __restrict__ hstate, const float* __restrict__ alpha,
             const float* __restrict__ Om, float* __restrict__ out,
             int t0g, int logTc, int Tc, int first, int last) {
    __shared__ __align__(16) char smem[65536];
    const int bx = blockIdx.x;
    if (bx < 128) {
        chain_body((float*)smem, (float(*)[132])(smem + 512), Br, hstate, alpha, Om, out,
                   Tc, first, last, bx, threadIdx.x);
    } else {
        int g = bx - 128;
        int qtile = g & (Tc - 1);
        int i = g >> logTc;
        gemm_body((f16*)smem, (f16*)(smem + 32768), Af2, Xh, Bw, t0g, logTc,
                  qtile, i, threadIdx.x);
    }
}

extern "C" void kernel_launch(void* const* d_in, const int* in_sizes, int n_in,
                              void* d_out, int out_size, void* d_ws, size_t ws_size,
                              hipStream_t stream) {
    const float* x     = (const float*)d_in[0];
    const float* alpha = (const float*)d_in[1];
    const float* A     = (const float*)d_in[2];
    const float* Om    = (const float*)d_in[3];
    float* out = (float*)d_out;

    char* ws = (char*)d_ws;
    f16*   Af2    = (f16*)ws;                          // 4 MB  [i][k][j]
    f16*   Xh     = (f16*)(ws + ((size_t)4 << 20));    // 16 MB [n*512+t][j]
    float* hstate = (float*)(ws + ((size_t)20 << 20)); // 64 KB

    int Tc = 16;   // double-buffered: 2 x 64 MB -> LLC resident with X+A
    while (Tc > 4 && ((size_t)21 << 20) + (((size_t)Tc << 22) * 2) > ws_size) Tc >>= 1;
    int logTc = 31 - __builtin_clz(Tc);
    int nch = 512 / Tc;
    f16* Bc[2];
    Bc[0] = (f16*)(ws + ((size_t)21 << 20));
    Bc[1] = (f16*)(ws + ((size_t)21 << 20) + ((size_t)Tc << 22));

    k_cvt_x<<<8192, 256, 0, stream>>>(x, Xh);
    k_cvt_A<<<8192, 256, 0, stream>>>(A, Af2);

    // prologue: gemm chunk 0 -> Bc[0]
    k_gemm<<<dim3(Tc, 128), 256, 0, stream>>>(Af2, Xh, Bc[0], 0, logTc);

    for (int c = 0; c < nch; ++c) {
        const f16* br = Bc[c & 1];
        if (c + 1 < nch) {
            // chain(c) + gemm(c+1) overlapped; stream order guarantees gemm(c) done.
            k_fused<<<128 + Tc * 128, 256, 0, stream>>>(
                Af2, Xh, Bc[(c + 1) & 1], br, hstate, alpha, Om, out,
                (c + 1) * Tc, logTc, Tc, c == 0, c == nch - 1);
        } else {
            k_chain<<<128, 256, 0, stream>>>(br, hstate, alpha, Om, out,
                                             Tc, c == 0, c == nch - 1);
        }
    }
    (void)in_sizes; (void)n_in; (void)out_size;
}